// Round 2
// baseline (4274.938 us; speedup 1.0000x reference)
//
#include <hip/hip_runtime.h>
#include <cstdint>
#include <cstddef>

#define NNODES 50000

// ---------------- degree ----------------
__global__ void deg_count_kernel(const int* __restrict__ ei, int E,
                                 float* __restrict__ deg) {
  int i = blockIdx.x * blockDim.x + threadIdx.x;
  if (i < E) {
    int dst = ei[E + i];  // ei[1][i]
    unsafeAtomicAdd(&deg[dst], 1.0f);
  }
}

__global__ void deg_finish_kernel(float* __restrict__ dinv, float* __restrict__ dinv2, int n) {
  int i = blockIdx.x * blockDim.x + threadIdx.x;
  if (i < n) {
    float d = dinv[i] + 1.0f;   // +1 self-loop
    dinv[i]  = rsqrtf(d);
    dinv2[i] = 1.0f / d;
  }
}

// ---------------- GEMM (fp32, 64x64 tile) + self-loop epilogue ----------------
// H[M,Nc] = A[M,K] @ W[K,Nc]; AGG = H * dinv2[row]  (self-loop init)
__global__ __launch_bounds__(256) void gemm_fused_kernel(
    const float* __restrict__ A, const float* __restrict__ W,
    float* __restrict__ H, float* __restrict__ AGG,
    const float* __restrict__ dinv2, int M, int K, int Nc) {
  __shared__ float As[64][17];
  __shared__ float Bs[16][65];
  const int row0 = blockIdx.x * 64;
  const int col0 = blockIdx.y * 64;
  const int tid = threadIdx.x;
  const int ty = tid >> 4, tx = tid & 15;
  float acc[4][4] = {};
  for (int k0 = 0; k0 < K; k0 += 16) {
#pragma unroll
    for (int q = 0; q < 4; q++) {
      int idx = tid + q * 256;
      int r = idx >> 4, c = idx & 15;
      int gr = row0 + r;
      As[r][c] = (gr < M) ? A[(size_t)gr * K + (k0 + c)] : 0.0f;
    }
#pragma unroll
    for (int q = 0; q < 4; q++) {
      int idx = tid + q * 256;
      int r = idx >> 6, c = idx & 63;
      Bs[r][c] = W[(size_t)(k0 + r) * Nc + (col0 + c)];
    }
    __syncthreads();
#pragma unroll
    for (int kk = 0; kk < 16; kk++) {
      float a[4], b[4];
#pragma unroll
      for (int i = 0; i < 4; i++) a[i] = As[ty * 4 + i][kk];
#pragma unroll
      for (int j = 0; j < 4; j++) b[j] = Bs[kk][tx * 4 + j];
#pragma unroll
      for (int i = 0; i < 4; i++)
#pragma unroll
        for (int j = 0; j < 4; j++)
          acc[i][j] += a[i] * b[j];
    }
    __syncthreads();
  }
#pragma unroll
  for (int i = 0; i < 4; i++) {
    int gr = row0 + ty * 4 + i;
    if (gr >= M) continue;
    float sc = dinv2[gr];
#pragma unroll
    for (int j = 0; j < 4; j++) {
      int gc = col0 + tx * 4 + j;
      size_t o = (size_t)gr * Nc + gc;
      float val = acc[i][j];
      H[o] = val;
      AGG[o] = val * sc;
    }
  }
}

// ---------------- edge scatter: AGG[dst] += H[src] * dinv[src]*dinv[dst] ----------------
__global__ void scatter_kernel(const int* __restrict__ ei, int E,
                               const float* __restrict__ H, float* __restrict__ AGG,
                               const float* __restrict__ dinv, int logd) {
  size_t idx = (size_t)blockIdx.x * blockDim.x + threadIdx.x;
  size_t total = ((size_t)E) << logd;
  if (idx >= total) return;
  int e = (int)(idx >> logd);
  int j = (int)(idx & ((1u << logd) - 1));
  int src = ei[e];
  int dst = ei[E + e];
  float norm = dinv[src] * dinv[dst];
  unsafeAtomicAdd(&AGG[((size_t)dst << logd) + j], H[((size_t)src << logd) + j] * norm);
}

// ---------------- BN(+bias)(+ReLU) in place ----------------
// out = ((x + B) - m) * g*rsqrt(v+eps) + bt
__global__ void bn_relu_kernel(float* __restrict__ AGG,
                               const float* __restrict__ Bb, const float* __restrict__ g,
                               const float* __restrict__ bt, const float* __restrict__ m,
                               const float* __restrict__ v, size_t total, int cmask, int relu) {
  size_t idx = (size_t)blockIdx.x * blockDim.x + threadIdx.x;
  if (idx >= total) return;
  int j = (int)(idx & (size_t)cmask);
  float a = g[j] * rsqrtf(v[j] + 1e-5f);
  float val = (AGG[idx] + Bb[j] - m[j]) * a + bt[j];
  if (relu) val = fmaxf(val, 0.0f);
  AGG[idx] = val;
}

// ---------------- layer-3: BN (no relu) fused with mean-pool (sum via atomics) ----------------
__global__ void bn_pool_kernel(const float* __restrict__ AGG,
                               const float* __restrict__ Bb, const float* __restrict__ g,
                               const float* __restrict__ bt, const float* __restrict__ m,
                               const float* __restrict__ v, int M, float* __restrict__ emb) {
  int ch = threadIdx.x & 63;
  int sub = threadIdx.x >> 6;  // 0..3
  float a = g[ch] * rsqrtf(v[ch] + 1e-5f);
  float sh = (Bb[ch] - m[ch]) * a + bt[ch];
  float acc = 0.0f;
  for (int r = blockIdx.x * 4 + sub; r < M; r += gridDim.x * 4)
    acc += AGG[(size_t)r * 64 + ch] * a + sh;
  __shared__ float red[256];
  red[threadIdx.x] = acc;
  __syncthreads();
  if (sub == 0)
    unsafeAtomicAdd(&emb[ch], red[ch] + red[64 + ch] + red[128 + ch] + red[192 + ch]);
}

// ---------------- head: fuse + cls + reg ----------------
__global__ void head_kernel(const float* __restrict__ emb, const float* __restrict__ fuse_W,
                            const float* __restrict__ fuse_b, const float* __restrict__ cls_W,
                            const float* __restrict__ cls_b, const float* __restrict__ reg_W,
                            const float* __restrict__ reg_b, float* __restrict__ out) {
  __shared__ float e[192];
  __shared__ float fused[64];
  int t = threadIdx.x;
  if (t < 192) e[t] = emb[t] * (1.0f / (float)NNODES);
  __syncthreads();
  if (t < 64) {
    float acc = fuse_b[t];
    for (int k = 0; k < 192; k++) acc += e[k] * fuse_W[k * 64 + t];
    fused[t] = fmaxf(acc, 0.0f);
  }
  __syncthreads();
  if (t < 10) {
    float acc = cls_b[t];
    for (int k = 0; k < 64; k++) acc += fused[k] * cls_W[k * 10 + t];
    out[t] = acc;
  }
  if (t == 64) {
    float acc = reg_b[0];
    for (int k = 0; k < 64; k++) acc += fused[k] * reg_W[k];
    out[10] = 1.0f / (1.0f + expf(-acc));
  }
}

extern "C" void kernel_launch(void* const* d_in, const int* in_sizes, int n_in,
                              void* d_out, int out_size, void* d_ws, size_t ws_size,
                              hipStream_t stream) {
  const int N = NNODES;
  const float* xs[3] = {(const float*)d_in[0], (const float*)d_in[1], (const float*)d_in[2]};
  // NOTE: harness converts integer inputs to int32 (round-1 lesson: int64 cast -> OOB fault)
  const int* eis[3] = {(const int*)d_in[3], (const int*)d_in[4], (const int*)d_in[5]};
  int Es[3];
  for (int s = 0; s < 3; s++) Es[s] = in_sizes[3 + s] / 2;

  // per-LAYER parameter arrays (each holds 3 branch slices)
  const float* Wp[3]  = {(const float*)d_in[6],  (const float*)d_in[12], (const float*)d_in[18]};
  const float* Bp[3]  = {(const float*)d_in[7],  (const float*)d_in[13], (const float*)d_in[19]};
  const float* gp[3]  = {(const float*)d_in[8],  (const float*)d_in[14], (const float*)d_in[20]};
  const float* btp[3] = {(const float*)d_in[9],  (const float*)d_in[15], (const float*)d_in[21]};
  const float* mp[3]  = {(const float*)d_in[10], (const float*)d_in[16], (const float*)d_in[22]};
  const float* vp[3]  = {(const float*)d_in[11], (const float*)d_in[17], (const float*)d_in[23]};
  const float* fuse_W = (const float*)d_in[24];
  const float* fuse_b = (const float*)d_in[25];
  const float* cls_W  = (const float*)d_in[26];
  const float* cls_b  = (const float*)d_in[27];
  const float* reg_W  = (const float*)d_in[28];
  const float* reg_b  = (const float*)d_in[29];

  const int dins[3]  = {1024, 256, 128};
  const int douts[3] = {256, 128, 64};
  const int logds[3] = {8, 7, 6};

  size_t off = 0;
  auto alloc = [&](size_t nfloats) {
    float* p = (float*)((char*)d_ws + off);
    off += ((nfloats * sizeof(float)) + 255) & ~(size_t)255;
    return p;
  };
  float* dinv_all  = alloc(3 * (size_t)N);
  float* dinv2_all = alloc(3 * (size_t)N);
  float* emb       = alloc(192);
  float* buf0 = alloc((size_t)N * 256);  // H (max dout = 256)
  float* buf1 = alloc((size_t)N * 256);  // AGG (layers 0,2)
  float* buf2 = alloc((size_t)N * 128);  // AGG (layer 1)
  (void)ws_size; (void)n_in; (void)out_size;

  hipMemsetAsync(dinv_all, 0, 3 * (size_t)N * sizeof(float), stream);
  hipMemsetAsync(emb, 0, 192 * sizeof(float), stream);

  for (int s = 0; s < 3; s++)
    deg_count_kernel<<<(Es[s] + 255) / 256, 256, 0, stream>>>(eis[s], Es[s],
                                                              dinv_all + (size_t)s * N);
  deg_finish_kernel<<<(3 * N + 255) / 256, 256, 0, stream>>>(dinv_all, dinv2_all, 3 * N);

  for (int s = 0; s < 3; s++) {
    const float* dinv  = dinv_all  + (size_t)s * N;
    const float* dinv2 = dinv2_all + (size_t)s * N;
    const float* inbuf = xs[s];
    for (int l = 0; l < 3; l++) {
      int K = dins[l], C = douts[l], logd = logds[l];
      const float* W  = Wp[l]  + (size_t)s * K * C;
      const float* Bb = Bp[l]  + (size_t)s * C;
      const float* g  = gp[l]  + (size_t)s * C;
      const float* bt = btp[l] + (size_t)s * C;
      const float* m  = mp[l]  + (size_t)s * C;
      const float* v  = vp[l]  + (size_t)s * C;
      float* H   = buf0;
      float* AGG = (l == 1) ? buf2 : buf1;

      dim3 grid((N + 63) / 64, C / 64);
      gemm_fused_kernel<<<grid, 256, 0, stream>>>(inbuf, W, H, AGG, dinv2, N, K, C);

      size_t total = ((size_t)Es[s]) << logd;
      scatter_kernel<<<(unsigned)((total + 255) / 256), 256, 0, stream>>>(eis[s], Es[s], H, AGG,
                                                                          dinv, logd);
      if (l < 2) {
        size_t tot2 = (size_t)N * C;
        bn_relu_kernel<<<(unsigned)((tot2 + 255) / 256), 256, 0, stream>>>(AGG, Bb, g, bt, m, v,
                                                                           tot2, C - 1, 1);
        inbuf = AGG;
      } else {
        bn_pool_kernel<<<256, 256, 0, stream>>>(AGG, Bb, g, bt, m, v, N, emb + s * 64);
      }
    }
  }

  head_kernel<<<1, 192, 0, stream>>>(emb, fuse_W, fuse_b, cls_W, cls_b, reg_W, reg_b,
                                     (float*)d_out);
}